// Round 5
// baseline (1055.763 us; speedup 1.0000x reference)
//
#include <hip/hip_runtime.h>
#include <hip/hip_bf16.h>
#include <cstdint>

#define B_ 2
#define T_ 2048
#define HID 2048
#define NH 6
#define DK 256
#define DV 512
#define KEY_DIM (NH*DK)   // 1536
#define VAL_DIM (NH*DV)   // 3072
#define EPS_ 1e-5f
#define SCALE_ 0.0625f
#define MT (B_*T_)        // 4096
#define CC 64             // chunk length
#define NC (T_/CC)        // 32 chunks per batch row

typedef __attribute__((ext_vector_type(8))) short short8;
typedef __attribute__((ext_vector_type(4))) float floatx4;
typedef __attribute__((ext_vector_type(4))) unsigned int uint4v;

union Pk8 { unsigned short us[8]; uint4v v; };

__device__ inline unsigned short f32_to_bf16(float f) {
    union { float f; unsigned int u; } v; v.f = f;
    unsigned int u = v.u;
    u += 0x7fffu + ((u >> 16) & 1u);
    return (unsigned short)(u >> 16);
}

__device__ inline float bf16_to_f32(unsigned short u) {
    union { unsigned int u; float f; } v; v.u = ((unsigned int)u) << 16;
    return v.f;
}

__device__ inline float silu_f(float x) { return x / (1.f + expf(-x)); }

// async global -> LDS, 16 bytes per lane (dest = wave-uniform base + lane*16)
__device__ inline void gl_lds16(const unsigned short* g, unsigned short* l) {
    __builtin_amdgcn_global_load_lds(
        (const __attribute__((address_space(1))) unsigned int*)g,
        (__attribute__((address_space(3))) unsigned int*)l, 16, 0, 0);
}

// ---------------- convert f32 -> bf16 (elementwise) ----------------
__global__ __launch_bounds__(256) void cvt_bf16_kernel(const float* __restrict__ in,
                                                       unsigned short* __restrict__ out, int n) {
    int i = (blockIdx.x * 256 + threadIdx.x) * 4;
    if (i >= n) return;
    float4 v = *reinterpret_cast<const float4*>(in + i);
    ushort4 o;
    o.x = f32_to_bf16(v.x); o.y = f32_to_bf16(v.y);
    o.z = f32_to_bf16(v.z); o.w = f32_to_bf16(v.w);
    *reinterpret_cast<ushort4*>(out + i) = o;
}

// ---------------- transpose + convert: in f32 [K][N] -> out bf16 [N][K] ----------------
__global__ __launch_bounds__(256) void transpose_cvt_kernel(const float* __restrict__ in,
                                                            unsigned short* __restrict__ out,
                                                            int K, int N) {
    __shared__ float tile[64][65];
    int k0 = blockIdx.x * 64, n0 = blockIdx.y * 64;
    int r = threadIdx.x >> 2, c0 = (threadIdx.x & 3) * 16;
    const float* src = in + (size_t)(k0 + r) * N + n0 + c0;
#pragma unroll
    for (int j = 0; j < 16; j += 4) {
        float4 v = *reinterpret_cast<const float4*>(src + j);
        tile[r][c0 + j + 0] = v.x; tile[r][c0 + j + 1] = v.y;
        tile[r][c0 + j + 2] = v.z; tile[r][c0 + j + 3] = v.w;
    }
    __syncthreads();
    int n = threadIdx.x >> 2, kc = (threadIdx.x & 3) * 16;
    unsigned short* dst = out + (size_t)(n0 + n) * K + k0 + kc;
#pragma unroll
    for (int j = 0; j < 16; j += 4) {
        ushort4 o;
        o.x = f32_to_bf16(tile[kc + j + 0][n]);
        o.y = f32_to_bf16(tile[kc + j + 1][n]);
        o.z = f32_to_bf16(tile[kc + j + 2][n]);
        o.w = f32_to_bf16(tile[kc + j + 3][n]);
        *reinterpret_cast<ushort4*>(dst + j) = o;
    }
}

// ---------------- bf16 MFMA GEMM (m97 structure): C = A @ BT^T ----------------
#define BM 128
#define BN 128
#define BK 32

__global__ __launch_bounds__(256) void gemm_bf16_kernel(const unsigned short* __restrict__ A,
                                                        const unsigned short* __restrict__ BT,
                                                        float* __restrict__ C,
                                                        int M, int N, int K) {
    __shared__ __align__(16) unsigned short As[BM * BK];  // linear [128][32]
    __shared__ __align__(16) unsigned short Bs[BN * BK];
    int tid = threadIdx.x;
    int m0 = blockIdx.y * BM, n0 = blockIdx.x * BN;
    int wave = tid >> 6, lane = tid & 63;
    int wr = (wave >> 1) * 64, wc = (wave & 1) * 64;
    int l15 = lane & 15, lh = lane >> 4;

    // staging via global_load_lds: wave w, op o covers LDS bytes [o*4096 + w*1024 + lane*16]
    int srow = wave * 16 + (lane >> 2);
    int scol = (lane & 3) * 8;
    const unsigned short* agp0 = A + (size_t)(m0 + srow) * K + scol;
    const unsigned short* agp1 = A + (size_t)(m0 + srow + 64) * K + scol;
    const unsigned short* bgp0 = BT + (size_t)(n0 + srow) * K + scol;
    const unsigned short* bgp1 = BT + (size_t)(n0 + srow + 64) * K + scol;
    unsigned short* asl0 = As + wave * 512;
    unsigned short* asl1 = As + 2048 + wave * 512;
    unsigned short* bsl0 = Bs + wave * 512;
    unsigned short* bsl1 = Bs + 2048 + wave * 512;

    floatx4 acc[4][4];
#pragma unroll
    for (int m = 0; m < 4; m++)
#pragma unroll
        for (int n = 0; n < 4; n++) acc[m][n] = (floatx4){0.f, 0.f, 0.f, 0.f};

    for (int kt = 0; kt < K; kt += BK) {
        __syncthreads();
        gl_lds16(agp0 + kt, asl0);
        gl_lds16(agp1 + kt, asl1);
        gl_lds16(bgp0 + kt, bsl0);
        gl_lds16(bgp1 + kt, bsl1);
        __syncthreads();
        short8 a[4], b[4];
#pragma unroll
        for (int i = 0; i < 4; i++)
            a[i] = *reinterpret_cast<const short8*>(As + (wr + i * 16 + l15) * BK + lh * 8);
#pragma unroll
        for (int i = 0; i < 4; i++)
            b[i] = *reinterpret_cast<const short8*>(Bs + (wc + i * 16 + l15) * BK + lh * 8);
#pragma unroll
        for (int m = 0; m < 4; m++)
#pragma unroll
            for (int n = 0; n < 4; n++)
                acc[m][n] = __builtin_amdgcn_mfma_f32_16x16x32_bf16(a[m], b[n], acc[m][n], 0, 0, 0);
    }

#pragma unroll
    for (int m = 0; m < 4; m++)
#pragma unroll
        for (int n = 0; n < 4; n++) {
            int row = m0 + wr + m * 16 + lh * 4;
            int col = n0 + wc + n * 16 + l15;
#pragma unroll
            for (int j = 0; j < 4; j++)
                C[(size_t)(row + j) * N + col] = acc[m][n][j];
        }
}

// ---------------- a/b projections + softplus/sigmoid ----------------
__global__ __launch_bounds__(256) void ab_kernel(const float* __restrict__ x,
                                                 const float* __restrict__ wa,
                                                 const float* __restrict__ wb,
                                                 const float* __restrict__ A_log,
                                                 const float* __restrict__ dtb,
                                                 float* __restrict__ glog,
                                                 float* __restrict__ beta) {
    int bt = blockIdx.x, tid = threadIdx.x;
    const float* xr = x + (size_t)bt * HID;
    float pa[NH], pb[NH];
#pragma unroll
    for (int h = 0; h < NH; h++) { pa[h] = 0.f; pb[h] = 0.f; }
    for (int k = tid; k < HID; k += 256) {
        float xv = xr[k];
#pragma unroll
        for (int h = 0; h < NH; h++) {
            pa[h] = fmaf(xv, wa[k * NH + h], pa[h]);
            pb[h] = fmaf(xv, wb[k * NH + h], pb[h]);
        }
    }
    __shared__ float red[256][12];
#pragma unroll
    for (int h = 0; h < NH; h++) { red[tid][h] = pa[h]; red[tid][NH + h] = pb[h]; }
    __syncthreads();
    for (int s = 128; s > 0; s >>= 1) {
        if (tid < s)
#pragma unroll
            for (int j = 0; j < 12; j++) red[tid][j] += red[tid + s][j];
        __syncthreads();
    }
    if (tid < NH) {
        float a = red[0][tid] + dtb[tid];
        float sp = (a > 20.f) ? a : log1pf(expf(a));
        glog[(size_t)bt * NH + tid] = -expf(A_log[tid]) * sp;
        float bv = red[0][NH + tid];
        beta[(size_t)bt * NH + tid] = 1.f / (1.f + expf(-bv));
    }
}

// ---------------- causal conv(4) + SiLU + per-head l2norm (q,k) ----------------
__global__ __launch_bounds__(256) void conv_silu_l2norm_kernel(const float* __restrict__ in,
                                                               const float* __restrict__ w,
                                                               float* __restrict__ out) {
    int bt = blockIdx.x;
    int h = blockIdx.y;
    int t = bt & (T_ - 1);
    int c = h * DK + threadIdx.x;
    float4 wv = *reinterpret_cast<const float4*>(w + (size_t)c * 4);
    float acc = 0.f;
    if (t >= 3) {
        acc = in[(size_t)(bt - 3) * KEY_DIM + c] * wv.x
            + in[(size_t)(bt - 2) * KEY_DIM + c] * wv.y
            + in[(size_t)(bt - 1) * KEY_DIM + c] * wv.z
            + in[(size_t)(bt) * KEY_DIM + c] * wv.w;
    } else {
        if (t - 3 >= 0) acc = fmaf(in[(size_t)(bt - 3) * KEY_DIM + c], wv.x, acc);
        if (t - 2 >= 0) acc = fmaf(in[(size_t)(bt - 2) * KEY_DIM + c], wv.y, acc);
        if (t - 1 >= 0) acc = fmaf(in[(size_t)(bt - 1) * KEY_DIM + c], wv.z, acc);
        acc = fmaf(in[(size_t)bt * KEY_DIM + c], wv.w, acc);
    }
    float s = silu_f(acc);
    float ss = s * s;
#pragma unroll
    for (int m = 1; m < 64; m <<= 1) ss += __shfl_xor(ss, m);
    __shared__ float wsum[4];
    if ((threadIdx.x & 63) == 0) wsum[threadIdx.x >> 6] = ss;
    __syncthreads();
    float tot = wsum[0] + wsum[1] + wsum[2] + wsum[3];
    float r = 1.f / fmaxf(sqrtf(tot), 1e-6f);
    out[(size_t)bt * KEY_DIM + c] = s * r;
}

// ---------------- causal conv(4) + SiLU (v) ----------------
__global__ __launch_bounds__(256) void conv_silu_kernel(const float* __restrict__ in,
                                                        const float* __restrict__ w,
                                                        float* __restrict__ out) {
    int bt = blockIdx.x;
    int c = blockIdx.y * 256 + threadIdx.x;
    int t = bt & (T_ - 1);
    float4 wv = *reinterpret_cast<const float4*>(w + (size_t)c * 4);
    float acc = 0.f;
    if (t >= 3) {
        acc = in[(size_t)(bt - 3) * VAL_DIM + c] * wv.x
            + in[(size_t)(bt - 2) * VAL_DIM + c] * wv.y
            + in[(size_t)(bt - 1) * VAL_DIM + c] * wv.z
            + in[(size_t)(bt) * VAL_DIM + c] * wv.w;
    } else {
        if (t - 3 >= 0) acc = fmaf(in[(size_t)(bt - 3) * VAL_DIM + c], wv.x, acc);
        if (t - 2 >= 0) acc = fmaf(in[(size_t)(bt - 2) * VAL_DIM + c], wv.y, acc);
        if (t - 1 >= 0) acc = fmaf(in[(size_t)(bt - 1) * VAL_DIM + c], wv.z, acc);
        acc = fmaf(in[(size_t)bt * VAL_DIM + c], wv.w, acc);
    }
    out[(size_t)bt * VAL_DIM + c] = silu_f(acc);
}

// ================= chunked gated delta rule =================
// Pass 1 (chunk-parallel): per (bh, chunk): decays, KK^T/QK^T (MFMA), M,
// T = (I+M)^-1 (register/readlane forward substitution), pre-scaled bf16 operands.
__global__ __launch_bounds__(256) void chunk_prep_kernel(
    const float* __restrict__ QC, const float* __restrict__ KC, const float* __restrict__ VC,
    const float* __restrict__ GL, const float* __restrict__ BE,
    unsigned short* __restrict__ Qg, unsigned short* __restrict__ KB,
    unsigned short* __restrict__ KlT, unsigned short* __restrict__ Tm,
    unsigned short* __restrict__ Am, unsigned short* __restrict__ BVT,
    float* __restrict__ gend) {
    int c = blockIdx.x;       // chunk within batch-row
    int bh = blockIdx.y;      // b*NH + h
    int b = bh / NH, h = bh % NH;
    size_t idx = (size_t)bh * NC + c;
    int bt0 = b * T_ + c * CC;

    __shared__ __align__(16) char ldsbuf[64 * 264 * 2 * 2];
    unsigned short* Kb = (unsigned short*)ldsbuf;
    unsigned short* Qb = (unsigned short*)(ldsbuf + 33792);
    float* Vst = (float*)ldsbuf;
    float* Msf = (float*)(ldsbuf + 33792);
    unsigned short* Ts_lds = (unsigned short*)(ldsbuf + 50432);
    __shared__ float gc[64], es[64], bb_s[64], gtmp[64];

    int tid = threadIdx.x, wave = tid >> 6, lane = tid & 63;
    int l15 = lane & 15, lh = lane >> 4;

    if (tid < 64) {
        gtmp[tid] = GL[(size_t)(bt0 + tid) * NH + h];
        bb_s[tid] = BE[(size_t)(bt0 + tid) * NH + h];
    }

    // stage K, Q chunk as bf16 [64][264]
    {
        int r = tid >> 2, seg = (tid & 3) * 64;
        const float* ksrc = KC + (size_t)(bt0 + r) * KEY_DIM + h * DK + seg;
        const float* qsrc = QC + (size_t)(bt0 + r) * KEY_DIM + h * DK + seg;
#pragma unroll
        for (int jj = 0; jj < 8; jj++) {
            float4 a = *reinterpret_cast<const float4*>(ksrc + jj * 8);
            float4 a2 = *reinterpret_cast<const float4*>(ksrc + jj * 8 + 4);
            Pk8 pk;
            pk.us[0] = f32_to_bf16(a.x);  pk.us[1] = f32_to_bf16(a.y);
            pk.us[2] = f32_to_bf16(a.z);  pk.us[3] = f32_to_bf16(a.w);
            pk.us[4] = f32_to_bf16(a2.x); pk.us[5] = f32_to_bf16(a2.y);
            pk.us[6] = f32_to_bf16(a2.z); pk.us[7] = f32_to_bf16(a2.w);
            *reinterpret_cast<uint4v*>(Kb + r * 264 + seg + jj * 8) = pk.v;
            float4 qa = *reinterpret_cast<const float4*>(qsrc + jj * 8);
            float4 qa2 = *reinterpret_cast<const float4*>(qsrc + jj * 8 + 4);
            pk.us[0] = f32_to_bf16(qa.x);  pk.us[1] = f32_to_bf16(qa.y);
            pk.us[2] = f32_to_bf16(qa.z);  pk.us[3] = f32_to_bf16(qa.w);
            pk.us[4] = f32_to_bf16(qa2.x); pk.us[5] = f32_to_bf16(qa2.y);
            pk.us[6] = f32_to_bf16(qa2.z); pk.us[7] = f32_to_bf16(qa2.w);
            *reinterpret_cast<uint4v*>(Qb + r * 264 + seg + jj * 8) = pk.v;
        }
    }
    __syncthreads();

    // wave 0: shuffle-based inclusive prefix sum of g
    if (wave == 0) {
        float xg = gtmp[lane];
#pragma unroll
        for (int off = 1; off < 64; off <<= 1) {
            float yg = __shfl_up(xg, off, 64);
            if (lane >= off) xg += yg;
        }
        gc[lane] = xg;
    }

    // KK^T and QK^T via MFMA (wave w owns t-rows 16w..16w+15)
    floatx4 kkf[4], qkf[4];
#pragma unroll
    for (int nt = 0; nt < 4; nt++) { kkf[nt] = (floatx4){0,0,0,0}; qkf[nt] = (floatx4){0,0,0,0}; }
#pragma unroll
    for (int kk = 0; kk < 8; kk++) {
        short8 ak = *reinterpret_cast<const short8*>(Kb + (wave * 16 + l15) * 264 + kk * 32 + lh * 8);
        short8 aq = *reinterpret_cast<const short8*>(Qb + (wave * 16 + l15) * 264 + kk * 32 + lh * 8);
#pragma unroll
        for (int nt = 0; nt < 4; nt++) {
            short8 bk = *reinterpret_cast<const short8*>(Kb + (nt * 16 + l15) * 264 + kk * 32 + lh * 8);
            kkf[nt] = __builtin_amdgcn_mfma_f32_16x16x32_bf16(ak, bk, kkf[nt], 0, 0, 0);
            qkf[nt] = __builtin_amdgcn_mfma_f32_16x16x32_bf16(aq, bk, qkf[nt], 0, 0, 0);
        }
    }
    __syncthreads();   // gc ready; all Qb/Kb MFMA reads done

    // Qg = SCALE*gamma_t*q ; KB = b_t*gamma_t*k  (rescale from staged bf16 tiles)
    {
        int r = tid >> 2, seg = (tid & 3) * 64;
        float gmm = __expf(gc[r]);
        float qs = SCALE_ * gmm, ksc = bb_s[r] * gmm;
#pragma unroll
        for (int jj = 0; jj < 8; jj++) {
            Pk8 qi, ki, qo, ko;
            qi.v = *reinterpret_cast<const uint4v*>(Qb + r * 264 + seg + jj * 8);
            ki.v = *reinterpret_cast<const uint4v*>(Kb + r * 264 + seg + jj * 8);
#pragma unroll
            for (int e = 0; e < 8; e++) {
                qo.us[e] = f32_to_bf16(bf16_to_f32(qi.us[e]) * qs);
                ko.us[e] = f32_to_bf16(bf16_to_f32(ki.us[e]) * ksc);
            }
            *reinterpret_cast<uint4v*>(Qg + idx * 16384 + r * 256 + seg + jj * 8) = qo.v;
            *reinterpret_cast<uint4v*>(KB + idx * 16384 + r * 256 + seg + jj * 8) = ko.v;
        }
    }
    if (tid < 64) es[tid] = __expf(gc[63] - gc[tid]);
    __syncthreads();   // Qb reads complete before Msf overlay

    // M (LDS overlay over Qb) and A (global bf16)
#pragma unroll
    for (int nt = 0; nt < 4; nt++)
#pragma unroll
        for (int j = 0; j < 4; j++) {
            int t2 = wave * 16 + lh * 4 + j;
            int s2 = nt * 16 + l15;
            float dec = (s2 <= t2) ? __expf(gc[t2] - gc[s2]) : 0.f;
            Msf[t2 * 65 + s2] = (s2 < t2) ? bb_s[t2] * dec * kkf[nt][j] : 0.f;
            float av = (s2 <= t2) ? SCALE_ * dec * qkf[nt][j] : 0.f;
            Am[idx * 4096 + t2 * 64 + s2] = f32_to_bf16(av);
        }
    __syncthreads();

    // T = (I+M)^-1 by register/readlane forward substitution.
    {
        int t = lane;
        float a[16];
#pragma unroll
        for (int j2 = 0; j2 < 16; j2++) a[j2] = 0.f;
        float mcur = Msf[t * 65 + 0];
        for (int s = 0; s < 63; s++) {
            float mnext = Msf[t * 65 + s + 1];
            float m = (t > s) ? mcur : 0.f;
#pragma unroll
            for (int j2 = 0; j2 < 16; j2++) {
                int jg = 4 * j2 + wave;       // wave-uniform
                if (jg < s) {
                    float ra = __int_as_float(
                        __builtin_amdgcn_readlane(__float_as_int(a[j2]), s));
                    a[j2] = fmaf(m, -ra, a[j2]);
                } else if (jg == s) {
                    a[j2] += m;               // T[s][s] = 1
                }
            }
            mcur = mnext;
        }
#pragma unroll
        for (int j2 = 0; j2 < 16; j2++) {
            int jg = 4 * j2 + wave;
            float v = (t == jg) ? 1.f : ((jg < t) ? -a[j2] : 0.f);
            Ts_lds[t * 72 + jg] = f32_to_bf16(v);
        }
    }
    __syncthreads();

    // store T (bf16, coalesced)
    {
        int rr = tid >> 2, sseg = (tid & 3) * 16;
        *reinterpret_cast<uint4v*>(Tm + idx * 4096 + rr * 64 + sseg) =
            *reinterpret_cast<const uint4v*>(Ts_lds + rr * 72 + sseg);
        *reinterpret_cast<uint4v*>(Tm + idx * 4096 + rr * 64 + sseg + 8) =
            *reinterpret_cast<const uint4v*>(Ts_lds + rr * 72 + sseg + 8);
    }
    // KlT[dk][s] = k_s[dk] * (gammaEnd/gamma_s)
    {
        int dk = tid;
#pragma unroll
        for (int sb = 0; sb < 8; sb++) {
            Pk8 pk;
#pragma unroll
            for (int e = 0; e < 8; e++) {
                int s = sb * 8 + e;
                pk.us[e] = f32_to_bf16(bf16_to_f32(Kb[s * 264 + dk]) * es[s]);
            }
            *reinterpret_cast<uint4v*>(KlT + idx * 16384 + dk * 64 + sb * 8) = pk.v;
        }
    }
    // BVT[dv][c] = b_c * v_c[dv] (transpose through LDS, two halves)
    for (int hv = 0; hv < 2; hv++) {
        __syncthreads();
        int r = tid >> 2, seg = (tid & 3) * 64;
        const float* vsrc = VC + (size_t)(bt0 + r) * VAL_DIM + h * DV + hv * 256 + seg;
#pragma unroll
        for (int jj = 0; jj < 16; jj++)
            *reinterpret_cast<float4*>(Vst + r * 264 + seg + jj * 4) =
                *reinterpret_cast<const float4*>(vsrc + jj * 4);
        __syncthreads();
#pragma unroll
        for (int sb = 0; sb < 8; sb++) {
            Pk8 pk;
#pragma unroll
            for (int e = 0; e < 8; e++) {
                int s = sb * 8 + e;
                pk.us[e] = f32_to_bf16(Vst[s * 264 + tid] * bb_s[s]);
            }
            *reinterpret_cast<uint4v*>(BVT + idx * 32768 + (size_t)(hv * 256 + tid) * 64 + sb * 8) = pk.v;
        }
    }
    if (tid == 0) gend[idx] = __expf(gc[63]);
}

// Pass 2: sequential over chunks. Block = 2 waves; each wave owns a FULL
// 16-dv x 256-dk state strip (full t-range) -> W/U/state/O phases are
// wave-local (no barriers). Only Qg/KB/KlT staging uses 2 barriers/chunk.
__global__ __launch_bounds__(128, 1) void chunk_scan_kernel(
    const unsigned short* __restrict__ Qg, const unsigned short* __restrict__ KBp,
    const unsigned short* __restrict__ KlTp, const unsigned short* __restrict__ Tmp_,
    const unsigned short* __restrict__ Amp_, const unsigned short* __restrict__ BVTp,
    const float* __restrict__ gendp, float* __restrict__ O) {
    int slice = blockIdx.x;   // 0..15 (32 dv per block)
    int bh = blockIdx.y;      // 0..11
    int b = bh / NH, h = bh % NH;
    int tid = threadIdx.x, wave = tid >> 6, lane = tid & 63;
    int l15 = lane & 15, lh = lane >> 4;
    int dvbase = slice * 32 + wave * 16;   // wave's dv strip

    __shared__ __align__(16) unsigned short QgB[64 * 264];
    __shared__ __align__(16) unsigned short KBB[64 * 264];
    __shared__ __align__(16) unsigned short KlTB[256 * 72];
    __shared__ __align__(16) unsigned short SbT[2][16 * 264];
    __shared__ __align__(16) unsigned short Wb[2][16 * 72];
    __shared__ __align__(16) unsigned short Ub[2][16 * 72];
    __shared__ __align__(16) float Ost[2][64 * 20];

    unsigned short* sbt = SbT[wave];
    unsigned short* wb  = Wb[wave];
    unsigned short* ub  = Ub[wave];
    float* ost = Ost[wave];

    floatx4 st[16];
#pragma unroll
    for (int i = 0; i < 16; i++) st[i] = (floatx4){0.f, 0.f, 0.f, 0.f};
    for (int i = lane; i < 16 * 264; i += 64) sbt[i] = 0;

    int r = tid >> 1, seg = (tid & 1) * 128;   // staging row / 128-col half
    size_t idx0 = (size_t)bh * NC;

    // prologue: prefetch chunk 0 staging data into registers
    uint4v qv[16], kv[16], klv[16];
    {
        const unsigned short* qg = Qg + idx0 * 16384;
        const unsigned short* kb = KBp + idx0 * 16384;
        const unsigned short* kl = KlTp + idx0 * 16384;
#pragma unroll
        for (int j = 0; j < 16; j++) {
            qv[j] = *reinterpret_cast<const uint4v*>(qg + r * 256 + seg + j * 8);
            kv[j] = *reinterpret_cast<const uint4v*>(kb + r * 256 + seg + j * 8);
        }
#pragma unroll
        for (int j = 0; j < 8; j++) {
            klv[j]     = *reinterpret_cast<const uint4v*>(kl + tid * 64 + j * 8);
            klv[j + 8] = *reinterpret_cast<const uint4v*>(kl + (tid + 128) * 64 + j * 8);
        }
    }

    for (int c = 0; c < NC; c++) {
        size_t idx = idx0 + c;
        const unsigned short* tm = Tmp_ + idx * 4096;
        const unsigned short* am = Amp_ + idx * 4096;
        const unsigned short* bvt = BVTp + idx * 32768;
        float ge = gendp[idx];

        __syncthreads();   // both waves finished reading staged buffers of c-1
#pragma unroll
        for (int j = 0; j < 16; j++) {
            *reinterpret_cast<uint4v*>(QgB + r * 264 + seg + j * 8) = qv[j];
            *reinterpret_cast<uint4v*>(KBB + r * 264 + seg + j * 8) = kv[j];
        }
#pragma unroll
        for (int j = 0; j < 8; j++) {
            *reinterpret_cast<uint4v*>(KlTB + tid * 72 + j * 8) = klv[j];
            *reinterpret_cast<uint4v*>(KlTB + (tid + 128) * 72 + j * 8) = klv[j + 8];
        }
        __syncthreads();   // staging visible

        // prefetch NEXT chunk's staging data (off the dependency chain)
        if (c + 1 < NC) {
            const unsigned short* qg2 = Qg + (idx + 1) * 16384;
            const unsigned short* kb2 = KBp + (idx + 1) * 16384;
            const unsigned short* kl2 = KlTp + (idx + 1) * 16384;
#pragma unroll
            for (int j = 0; j < 16; j++) {
                qv[j] = *reinterpret_cast<const uint4v*>(qg2 + r * 256 + seg + j * 8);
                kv[j] = *reinterpret_cast<const uint4v*>(kb2 + r * 256 + seg + j * 8);
            }
#pragma unroll
            for (int j = 0; j < 8; j++) {
                klv[j]     = *reinterpret_cast<const uint4v*>(kl2 + tid * 64 + j * 8);
                klv[j + 8] = *reinterpret_cast<const uint4v*>(kl2 + (tid + 128) * 64 + j * 8);
            }
        }

        // wave-local operands for current chunk
        short8 tfr[4][2], afr[4][2];
#pragma unroll
        for (int nt = 0; nt < 4; nt++)
#pragma unroll
            for (int kk = 0; kk < 2; kk++) {
                tfr[nt][kk] = *reinterpret_cast<const short8*>(tm + (nt * 16 + l15) * 64 + kk * 32 + lh * 8);
                afr[nt][kk] = *reinterpret_cast<const short8*>(am + (nt * 16 + l15) * 64 + kk * 32 + lh * 8);
            }
        float bvv[4][4];
#pragma unroll
        for (int nt = 0; nt < 4; nt++)
#pragma unroll
            for (int j = 0; j < 4; j++)
                bvv[nt][j] = bf16_to_f32(bvt[(size_t)(dvbase + lh * 4 + j) * 64 + nt * 16 + l15]);

        // -------- X2 = S^T*Qg , X1 = S^T*KB (A from own SbT; B from shared staging) --------
        floatx4 x2f[4], x1f[4];
#pragma unroll
        for (int nt = 0; nt < 4; nt++) { x2f[nt] = (floatx4){0,0,0,0}; x1f[nt] = (floatx4){0,0,0,0}; }
#pragma unroll
        for (int kk = 0; kk < 8; kk++) {
            short8 af = *reinterpret_cast<const short8*>(sbt + l15 * 264 + kk * 32 + lh * 8);
#pragma unroll
            for (int nt = 0; nt < 4; nt++) {
                short8 bq = *reinterpret_cast<const short8*>(QgB + (nt * 16 + l15) * 264 + kk * 32 + lh * 8);
                short8 bk = *reinterpret_cast<const short8*>(KBB + (nt * 16 + l15) * 264 + kk * 32 + lh * 8);
                x2f[nt] = __builtin_amdgcn_mfma_f32_16x16x32_bf16(af, bq, x2f[nt], 0, 0, 0);
                x1f[nt] = __builtin_amdgcn_mfma_f32_16x16x32_bf16(af, bk, x1f[nt], 0, 0, 0);
            }
        }

        // W = BV - X1 -> wave-local wb (no barrier: same-wave LDS is in-order)
#pragma unroll
        for (int nt = 0; nt < 4; nt++)
#pragma unroll
            for (int j = 0; j < 4; j++)
                wb[(lh * 4 + j) * 72 + nt * 16 + l15] = f32_to_bf16(bvv[nt][j] - x1f[nt][j]);

        // -------- U = W * T --------
        floatx4 uf[4];
#pragma unroll
        for (int nt = 0; nt < 4; nt++) uf[nt] = (floatx4){0,0,0,0};
#pragma unroll
        for (int kk = 0; kk < 2; kk++) {
            short8 af = *reinterpret_cast<const short8*>(wb + l15 * 72 + kk * 32 + lh * 8);
#pragma unroll
            for (int nt = 0; nt < 4; nt++)
                uf[nt] = __builtin_amdgcn_mfma_f32_16x16x32_bf16(af, tfr[nt][kk], uf[nt], 0, 0, 0);
        }
#pragma unroll
        for (int nt = 0; nt < 4; nt++)
#pragma unroll
            for (int j = 0; j < 4; j++)
                ub[(lh * 4 + j) * 72 + nt * 16 + l15] = f32_to_bf16(uf[nt][j]);

        // -------- state: S = gend*S + U*KlT --------
#pragma unroll
        for (int i = 0; i < 16; i++) st[i] = st[i] * ge;
#pragma unroll
        for (int kk = 0; kk < 2; kk++) {
            short8 af = *reinterpret_cast<const short8*>(ub + l15 * 72 + kk * 32 + lh * 8);
#pragma unroll
            for (int dkt = 0; dkt < 16; dkt++) {
                short8 bf = *reinterpret_cast<const short8*>(KlTB + (dkt * 16 + l15) * 72 + kk * 32 + lh * 8);
                st[dkt] = __builtin_amdgcn_mfma_f32_16x16x32_bf16(af, bf, st[dkt], 0, 0, 0);
            }
        }
        // bf16 shadow for next chunk (own region)
#pragma unroll
        for (int dkt = 0; dkt < 16; dkt++)
#pragma unroll
            for (int j = 0; j < 4; j++)
                sbt[(lh * 4 + j) * 264 + dkt * 16 + l15] = f32_to_bf16(st[dkt][j]);

        // -------- O = X2 + U*A --------
#pragma unroll
        for (int kk = 0; kk < 2; kk++) {
            short8 af = *reinterpret_cast<const short8*>(ub + l15 * 72 + kk * 32 + lh * 8);
#pragma unroll
            for (int nt = 0; nt < 4; nt++)
                x2f[nt] = __builtin_amdgcn_mfma_f32_16x16x32_bf16(af, afr[nt][kk], x2f[nt], 0, 0, 0);
        }
        // transpose [dv][t] -> [t][dv] through wave-local ost, then store
#pragma unroll
        for (int nt = 0; nt < 4; nt++)
#pragma unroll
            for (int j = 0; j < 4; j++)
                ost[(nt * 16 + l15) * 20 + lh * 4 + j] = x2f[nt][j];
        {
            float4 o0 = *reinterpret_cast<const float4*>(ost + lane * 20);
            float4 o1 = *reinterpret_cast<const float4*>(ost + lane * 20 + 4);
            float4 o2 = *reinterpret_cast<const float4*>(ost + lane * 20 + 8);
            float4 o3 = *reinterpret_cast<const float4*>(ost + lane * 20 + 12);
            size_t ga = ((size_t)(b * T_ + c * CC + lane)) * VAL_DIM + h * DV + dvbase;
            *reinterpret_cast<float4*>(O + ga)      = o0;
            *reinterpret_cast<float4*>(O + ga + 4)  = o1;
            *reinterpret_cast<float4*>(O + ga + 8)  = o2;
            *reinterpret_cast<float4*>(O + ga + 12) = o3;
        }
    }
}

// ---------------- gated RMSNorm * w * silu(g) -> bf16 ----------------
__global__ __launch_bounds__(256) void gated_norm_kernel(const float* __restrict__ o,
                                                         const float* __restrict__ g,
                                                         const float* __restrict__ nw,
                                                         unsigned short* __restrict__ out) {
    int bt = blockIdx.x, h = blockIdx.y, tid = threadIdx.x;
    const float* orow = o + (size_t)bt * VAL_DIM + h * DV;
    const float* grow = g + (size_t)bt * VAL_DIM + h * DV;
    float x0 = orow[tid], x1 = orow[tid + 256];
    float ss = x0 * x0 + x1 * x1;
#pragma unroll
    for (int m = 1; m < 64; m <<= 1) ss += __shfl_xor(ss, m);
    __shared__ float wsum[4];
    if ((tid & 63) == 0) wsum[tid >> 6] = ss;
    __syncthreads();
    float tot = wsum[0] + wsum[1] + wsum[2] + wsum[3];
    float r = rsqrtf(tot / (float)DV + EPS_);
    float o0 = x0 * r * nw[tid] * silu_f(grow[tid]);
    float o1 = x1 * r * nw[tid + 256] * silu_f(grow[tid + 256]);
    unsigned short* orow_o = out + (size_t)bt * VAL_DIM + h * DV;
    orow_o[tid] = f32_to_bf16(o0);
    orow_o[tid + 256] = f32_to_bf16(o1);
}

extern "C" void kernel_launch(void* const* d_in, const int* in_sizes, int n_in,
                              void* d_out, int out_size, void* d_ws, size_t ws_size,
                              hipStream_t stream) {
    const float* x     = (const float*)d_in[0];
    const float* w_q   = (const float*)d_in[1];
    const float* w_k   = (const float*)d_in[2];
    const float* w_v   = (const float*)d_in[3];
    const float* w_a   = (const float*)d_in[4];
    const float* w_b   = (const float*)d_in[5];
    const float* w_g   = (const float*)d_in[6];
    const float* w_o   = (const float*)d_in[7];
    const float* cq    = (const float*)d_in[8];
    const float* ck    = (const float*)d_in[9];
    const float* cv    = (const float*)d_in[10];
    const float* A_log = (const float*)d_in[11];
    const float* dtb   = (const float*)d_in[12];
    const float* nw    = (const float*)d_in[13];
    float* out = (float*)d_out;

    char* ws = (char*)d_ws;
    size_t off = 0;
    auto alloc = [&](size_t bytes) {
        char* p = ws + off;
        off += (bytes + 255) & ~(size_t)255;
        return p;
    };
    unsigned short* xb = (unsigned short*)alloc((size_t)MT * HID * 2);
    unsigned short* wT = (unsigned short*)alloc((size_t)VAL_DIM * HID * 2);
    float* P1 = (float*)alloc((size_t)MT * KEY_DIM * 4);
    float* QC = (float*)alloc((size_t)MT * KEY_DIM * 4);
    float* KC = (float*)alloc((size_t)MT * KEY_DIM * 4);
    float* P2 = (float*)alloc((size_t)MT * VAL_DIM * 4);
    float* VC = (float*)alloc((size_t)MT * VAL_DIM * 4);
    float* GL = (float*)alloc((size_t)MT * NH * 4);
    float* BE = (float*)alloc((size_t)MT * NH * 4);
    const int NCH = 12 * NC;
    unsigned short* KlT = (unsigned short*)alloc((size_t)NCH * 256 * 64 * 2);
    unsigned short* Tm  = (unsigned short*)alloc((size_t)NCH * 4096 * 2);
    unsigned short* Am  = (unsigned short*)alloc((size_t)NCH * 4096 * 2);
    unsigned short* BVT = (unsigned short*)alloc((size_t)NCH * 512 * 64 * 2);
    float* gend = (float*)alloc((size_t)NCH * 4);

    unsigned short* Qg = (unsigned short*)P1;
    unsigned short* KB = (unsigned short*)P1 + (size_t)NCH * 16384;
    float* OB = VC;
    unsigned short* ONB = (unsigned short*)P1;

    // x -> bf16
    cvt_bf16_kernel<<<(MT * HID) / 1024, 256, 0, stream>>>(x, xb, MT * HID);

    // q path
    transpose_cvt_kernel<<<dim3(HID / 64, KEY_DIM / 64), 256, 0, stream>>>(w_q, wT, HID, KEY_DIM);
    gemm_bf16_kernel<<<dim3(KEY_DIM / BN, MT / BM), 256, 0, stream>>>(xb, wT, P1, MT, KEY_DIM, HID);
    conv_silu_l2norm_kernel<<<dim3(MT, NH), 256, 0, stream>>>(P1, cq, QC);

    // k path
    transpose_cvt_kernel<<<dim3(HID / 64, KEY_DIM / 64), 256, 0, stream>>>(w_k, wT, HID, KEY_DIM);
    gemm_bf16_kernel<<<dim3(KEY_DIM / BN, MT / BM), 256, 0, stream>>>(xb, wT, P1, MT, KEY_DIM, HID);
    conv_silu_l2norm_kernel<<<dim3(MT, NH), 256, 0, stream>>>(P1, ck, KC);

    // v path
    transpose_cvt_kernel<<<dim3(HID / 64, VAL_DIM / 64), 256, 0, stream>>>(w_v, wT, HID, VAL_DIM);
    gemm_bf16_kernel<<<dim3(VAL_DIM / BN, MT / BM), 256, 0, stream>>>(xb, wT, P2, MT, VAL_DIM, HID);
    conv_silu_kernel<<<dim3(MT, VAL_DIM / 256), 256, 0, stream>>>(P2, cv, VC);

    // g path
    transpose_cvt_kernel<<<dim3(HID / 64, VAL_DIM / 64), 256, 0, stream>>>(w_g, wT, HID, VAL_DIM);
    gemm_bf16_kernel<<<dim3(VAL_DIM / BN, MT / BM), 256, 0, stream>>>(xb, wT, P2, MT, VAL_DIM, HID);

    // a/b projections (f32, exact)
    ab_kernel<<<MT, 256, 0, stream>>>(x, w_a, w_b, A_log, dtb, GL, BE);

    // chunked scan
    chunk_prep_kernel<<<dim3(NC, 12), 256, 0, stream>>>(QC, KC, VC, GL, BE,
                                                        Qg, KB, KlT, Tm, Am, BVT, gend);
    chunk_scan_kernel<<<dim3(16, 12), 128, 0, stream>>>(Qg, KB, KlT, Tm, Am, BVT, gend, OB);

    // gated RMSNorm -> bf16
    gated_norm_kernel<<<dim3(MT, NH), 256, 0, stream>>>(OB, P2, nw, ONB);

    // output projection
    transpose_cvt_kernel<<<dim3(VAL_DIM / 64, HID / 64), 256, 0, stream>>>(w_o, wT, VAL_DIM, HID);
    gemm_bf16_kernel<<<dim3(HID / BN, MT / BM), 256, 0, stream>>>(ONB, wT, out, MT, HID, VAL_DIM);
}

// Round 7
// 896.400 us; speedup vs baseline: 1.1778x; 1.1778x over previous
//
#include <hip/hip_runtime.h>
#include <hip/hip_bf16.h>
#include <cstdint>

#define B_ 2
#define T_ 2048
#define HID 2048
#define NH 6
#define DK 256
#define DV 512
#define KEY_DIM (NH*DK)   // 1536
#define VAL_DIM (NH*DV)   // 3072
#define EPS_ 1e-5f
#define SCALE_ 0.0625f
#define MT (B_*T_)        // 4096
#define CC 64             // chunk length
#define NC (T_/CC)        // 32 chunks per batch row

typedef __attribute__((ext_vector_type(8))) short short8;
typedef __attribute__((ext_vector_type(4))) float floatx4;
typedef __attribute__((ext_vector_type(4))) unsigned int uint4v;

union Pk8 { unsigned short us[8]; uint4v v; };

__device__ inline unsigned short f32_to_bf16(float f) {
    union { float f; unsigned int u; } v; v.f = f;
    unsigned int u = v.u;
    u += 0x7fffu + ((u >> 16) & 1u);
    return (unsigned short)(u >> 16);
}

__device__ inline float bf16_to_f32(unsigned short u) {
    union { unsigned int u; float f; } v; v.u = ((unsigned int)u) << 16;
    return v.f;
}

__device__ inline float silu_f(float x) { return x / (1.f + expf(-x)); }

// async global -> LDS, 16 bytes per lane (dest = wave-uniform base + lane*16)
__device__ inline void gl_lds16(const unsigned short* g, unsigned short* l) {
    __builtin_amdgcn_global_load_lds(
        (const __attribute__((address_space(1))) unsigned int*)g,
        (__attribute__((address_space(3))) unsigned int*)l, 16, 0, 0);
}

// ---------------- convert f32 -> bf16 (elementwise) ----------------
__global__ __launch_bounds__(256) void cvt_bf16_kernel(const float* __restrict__ in,
                                                       unsigned short* __restrict__ out, int n) {
    int i = (blockIdx.x * 256 + threadIdx.x) * 4;
    if (i >= n) return;
    float4 v = *reinterpret_cast<const float4*>(in + i);
    ushort4 o;
    o.x = f32_to_bf16(v.x); o.y = f32_to_bf16(v.y);
    o.z = f32_to_bf16(v.z); o.w = f32_to_bf16(v.w);
    *reinterpret_cast<ushort4*>(out + i) = o;
}

// ---------------- transpose + convert: in f32 [K][N] -> out bf16 [N][K] ----------------
__global__ __launch_bounds__(256) void transpose_cvt_kernel(const float* __restrict__ in,
                                                            unsigned short* __restrict__ out,
                                                            int K, int N) {
    __shared__ float tile[64][65];
    int k0 = blockIdx.x * 64, n0 = blockIdx.y * 64;
    int r = threadIdx.x >> 2, c0 = (threadIdx.x & 3) * 16;
    const float* src = in + (size_t)(k0 + r) * N + n0 + c0;
#pragma unroll
    for (int j = 0; j < 16; j += 4) {
        float4 v = *reinterpret_cast<const float4*>(src + j);
        tile[r][c0 + j + 0] = v.x; tile[r][c0 + j + 1] = v.y;
        tile[r][c0 + j + 2] = v.z; tile[r][c0 + j + 3] = v.w;
    }
    __syncthreads();
    int n = threadIdx.x >> 2, kc = (threadIdx.x & 3) * 16;
    unsigned short* dst = out + (size_t)(n0 + n) * K + k0 + kc;
#pragma unroll
    for (int j = 0; j < 16; j += 4) {
        ushort4 o;
        o.x = f32_to_bf16(tile[kc + j + 0][n]);
        o.y = f32_to_bf16(tile[kc + j + 1][n]);
        o.z = f32_to_bf16(tile[kc + j + 2][n]);
        o.w = f32_to_bf16(tile[kc + j + 3][n]);
        *reinterpret_cast<ushort4*>(dst + j) = o;
    }
}

// ---------------- bf16 MFMA GEMM (m97 structure): C = A @ BT^T ----------------
#define BM 128
#define BN 128
#define BK 32

__global__ __launch_bounds__(256) void gemm_bf16_kernel(const unsigned short* __restrict__ A,
                                                        const unsigned short* __restrict__ BT,
                                                        float* __restrict__ C,
                                                        int M, int N, int K) {
    __shared__ __align__(16) unsigned short As[BM * BK];  // linear [128][32]
    __shared__ __align__(16) unsigned short Bs[BN * BK];
    int tid = threadIdx.x;
    int m0 = blockIdx.y * BM, n0 = blockIdx.x * BN;
    int wave = tid >> 6, lane = tid & 63;
    int wr = (wave >> 1) * 64, wc = (wave & 1) * 64;
    int l15 = lane & 15, lh = lane >> 4;

    int srow = wave * 16 + (lane >> 2);
    int scol = (lane & 3) * 8;
    const unsigned short* agp0 = A + (size_t)(m0 + srow) * K + scol;
    const unsigned short* agp1 = A + (size_t)(m0 + srow + 64) * K + scol;
    const unsigned short* bgp0 = BT + (size_t)(n0 + srow) * K + scol;
    const unsigned short* bgp1 = BT + (size_t)(n0 + srow + 64) * K + scol;
    unsigned short* asl0 = As + wave * 512;
    unsigned short* asl1 = As + 2048 + wave * 512;
    unsigned short* bsl0 = Bs + wave * 512;
    unsigned short* bsl1 = Bs + 2048 + wave * 512;

    floatx4 acc[4][4];
#pragma unroll
    for (int m = 0; m < 4; m++)
#pragma unroll
        for (int n = 0; n < 4; n++) acc[m][n] = (floatx4){0.f, 0.f, 0.f, 0.f};

    for (int kt = 0; kt < K; kt += BK) {
        __syncthreads();
        gl_lds16(agp0 + kt, asl0);
        gl_lds16(agp1 + kt, asl1);
        gl_lds16(bgp0 + kt, bsl0);
        gl_lds16(bgp1 + kt, bsl1);
        __syncthreads();
        short8 a[4], b[4];
#pragma unroll
        for (int i = 0; i < 4; i++)
            a[i] = *reinterpret_cast<const short8*>(As + (wr + i * 16 + l15) * BK + lh * 8);
#pragma unroll
        for (int i = 0; i < 4; i++)
            b[i] = *reinterpret_cast<const short8*>(Bs + (wc + i * 16 + l15) * BK + lh * 8);
#pragma unroll
        for (int m = 0; m < 4; m++)
#pragma unroll
            for (int n = 0; n < 4; n++)
                acc[m][n] = __builtin_amdgcn_mfma_f32_16x16x32_bf16(a[m], b[n], acc[m][n], 0, 0, 0);
    }

#pragma unroll
    for (int m = 0; m < 4; m++)
#pragma unroll
        for (int n = 0; n < 4; n++) {
            int row = m0 + wr + m * 16 + lh * 4;
            int col = n0 + wc + n * 16 + l15;
#pragma unroll
            for (int j = 0; j < 4; j++)
                C[(size_t)(row + j) * N + col] = acc[m][n][j];
        }
}

// ---------------- a/b projections + softplus/sigmoid ----------------
__global__ __launch_bounds__(256) void ab_kernel(const float* __restrict__ x,
                                                 const float* __restrict__ wa,
                                                 const float* __restrict__ wb,
                                                 const float* __restrict__ A_log,
                                                 const float* __restrict__ dtb,
                                                 float* __restrict__ glog,
                                                 float* __restrict__ beta) {
    int bt = blockIdx.x, tid = threadIdx.x;
    const float* xr = x + (size_t)bt * HID;
    float pa[NH], pb[NH];
#pragma unroll
    for (int h = 0; h < NH; h++) { pa[h] = 0.f; pb[h] = 0.f; }
    for (int k = tid; k < HID; k += 256) {
        float xv = xr[k];
#pragma unroll
        for (int h = 0; h < NH; h++) {
            pa[h] = fmaf(xv, wa[k * NH + h], pa[h]);
            pb[h] = fmaf(xv, wb[k * NH + h], pb[h]);
        }
    }
    __shared__ float red[256][12];
#pragma unroll
    for (int h = 0; h < NH; h++) { red[tid][h] = pa[h]; red[tid][NH + h] = pb[h]; }
    __syncthreads();
    for (int s = 128; s > 0; s >>= 1) {
        if (tid < s)
#pragma unroll
            for (int j = 0; j < 12; j++) red[tid][j] += red[tid + s][j];
        __syncthreads();
    }
    if (tid < NH) {
        float a = red[0][tid] + dtb[tid];
        float sp = (a > 20.f) ? a : log1pf(expf(a));
        glog[(size_t)bt * NH + tid] = -expf(A_log[tid]) * sp;
        float bv = red[0][NH + tid];
        beta[(size_t)bt * NH + tid] = 1.f / (1.f + expf(-bv));
    }
}

// ---------------- causal conv(4) + SiLU + per-head l2norm (q,k) ----------------
__global__ __launch_bounds__(256) void conv_silu_l2norm_kernel(const float* __restrict__ in,
                                                               const float* __restrict__ w,
                                                               float* __restrict__ out) {
    int bt = blockIdx.x;
    int h = blockIdx.y;
    int t = bt & (T_ - 1);
    int c = h * DK + threadIdx.x;
    float4 wv = *reinterpret_cast<const float4*>(w + (size_t)c * 4);
    float acc = 0.f;
    if (t >= 3) {
        acc = in[(size_t)(bt - 3) * KEY_DIM + c] * wv.x
            + in[(size_t)(bt - 2) * KEY_DIM + c] * wv.y
            + in[(size_t)(bt - 1) * KEY_DIM + c] * wv.z
            + in[(size_t)(bt) * KEY_DIM + c] * wv.w;
    } else {
        if (t - 3 >= 0) acc = fmaf(in[(size_t)(bt - 3) * KEY_DIM + c], wv.x, acc);
        if (t - 2 >= 0) acc = fmaf(in[(size_t)(bt - 2) * KEY_DIM + c], wv.y, acc);
        if (t - 1 >= 0) acc = fmaf(in[(size_t)(bt - 1) * KEY_DIM + c], wv.z, acc);
        acc = fmaf(in[(size_t)bt * KEY_DIM + c], wv.w, acc);
    }
    float s = silu_f(acc);
    float ss = s * s;
#pragma unroll
    for (int m = 1; m < 64; m <<= 1) ss += __shfl_xor(ss, m);
    __shared__ float wsum[4];
    if ((threadIdx.x & 63) == 0) wsum[threadIdx.x >> 6] = ss;
    __syncthreads();
    float tot = wsum[0] + wsum[1] + wsum[2] + wsum[3];
    float r = 1.f / fmaxf(sqrtf(tot), 1e-6f);
    out[(size_t)bt * KEY_DIM + c] = s * r;
}

// ---------------- causal conv(4) + SiLU (v) ----------------
__global__ __launch_bounds__(256) void conv_silu_kernel(const float* __restrict__ in,
                                                        const float* __restrict__ w,
                                                        float* __restrict__ out) {
    int bt = blockIdx.x;
    int c = blockIdx.y * 256 + threadIdx.x;
    int t = bt & (T_ - 1);
    float4 wv = *reinterpret_cast<const float4*>(w + (size_t)c * 4);
    float acc = 0.f;
    if (t >= 3) {
        acc = in[(size_t)(bt - 3) * VAL_DIM + c] * wv.x
            + in[(size_t)(bt - 2) * VAL_DIM + c] * wv.y
            + in[(size_t)(bt - 1) * VAL_DIM + c] * wv.z
            + in[(size_t)(bt) * VAL_DIM + c] * wv.w;
    } else {
        if (t - 3 >= 0) acc = fmaf(in[(size_t)(bt - 3) * VAL_DIM + c], wv.x, acc);
        if (t - 2 >= 0) acc = fmaf(in[(size_t)(bt - 2) * VAL_DIM + c], wv.y, acc);
        if (t - 1 >= 0) acc = fmaf(in[(size_t)(bt - 1) * VAL_DIM + c], wv.z, acc);
        acc = fmaf(in[(size_t)bt * VAL_DIM + c], wv.w, acc);
    }
    out[(size_t)bt * VAL_DIM + c] = silu_f(acc);
}

// ================= chunked gated delta rule =================
// Pass 1 (chunk-parallel)
__global__ __launch_bounds__(256) void chunk_prep_kernel(
    const float* __restrict__ QC, const float* __restrict__ KC, const float* __restrict__ VC,
    const float* __restrict__ GL, const float* __restrict__ BE,
    unsigned short* __restrict__ Qg, unsigned short* __restrict__ KB,
    unsigned short* __restrict__ KlT, unsigned short* __restrict__ Tm,
    unsigned short* __restrict__ Am, unsigned short* __restrict__ BVT,
    float* __restrict__ gend) {
    int c = blockIdx.x;
    int bh = blockIdx.y;
    int b = bh / NH, h = bh % NH;
    size_t idx = (size_t)bh * NC + c;
    int bt0 = b * T_ + c * CC;

    __shared__ __align__(16) char ldsbuf[64 * 264 * 2 * 2];
    unsigned short* Kb = (unsigned short*)ldsbuf;
    unsigned short* Qb = (unsigned short*)(ldsbuf + 33792);
    float* Vst = (float*)ldsbuf;
    float* Msf = (float*)(ldsbuf + 33792);
    unsigned short* Ts_lds = (unsigned short*)(ldsbuf + 50432);
    __shared__ float gc[64], es[64], bb_s[64], gtmp[64];

    int tid = threadIdx.x, wave = tid >> 6, lane = tid & 63;
    int l15 = lane & 15, lh = lane >> 4;

    if (tid < 64) {
        gtmp[tid] = GL[(size_t)(bt0 + tid) * NH + h];
        bb_s[tid] = BE[(size_t)(bt0 + tid) * NH + h];
    }

    {
        int r = tid >> 2, seg = (tid & 3) * 64;
        const float* ksrc = KC + (size_t)(bt0 + r) * KEY_DIM + h * DK + seg;
        const float* qsrc = QC + (size_t)(bt0 + r) * KEY_DIM + h * DK + seg;
#pragma unroll
        for (int jj = 0; jj < 8; jj++) {
            float4 a = *reinterpret_cast<const float4*>(ksrc + jj * 8);
            float4 a2 = *reinterpret_cast<const float4*>(ksrc + jj * 8 + 4);
            Pk8 pk;
            pk.us[0] = f32_to_bf16(a.x);  pk.us[1] = f32_to_bf16(a.y);
            pk.us[2] = f32_to_bf16(a.z);  pk.us[3] = f32_to_bf16(a.w);
            pk.us[4] = f32_to_bf16(a2.x); pk.us[5] = f32_to_bf16(a2.y);
            pk.us[6] = f32_to_bf16(a2.z); pk.us[7] = f32_to_bf16(a2.w);
            *reinterpret_cast<uint4v*>(Kb + r * 264 + seg + jj * 8) = pk.v;
            float4 qa = *reinterpret_cast<const float4*>(qsrc + jj * 8);
            float4 qa2 = *reinterpret_cast<const float4*>(qsrc + jj * 8 + 4);
            pk.us[0] = f32_to_bf16(qa.x);  pk.us[1] = f32_to_bf16(qa.y);
            pk.us[2] = f32_to_bf16(qa.z);  pk.us[3] = f32_to_bf16(qa.w);
            pk.us[4] = f32_to_bf16(qa2.x); pk.us[5] = f32_to_bf16(qa2.y);
            pk.us[6] = f32_to_bf16(qa2.z); pk.us[7] = f32_to_bf16(qa2.w);
            *reinterpret_cast<uint4v*>(Qb + r * 264 + seg + jj * 8) = pk.v;
        }
    }
    __syncthreads();

    if (wave == 0) {
        float xg = gtmp[lane];
#pragma unroll
        for (int off = 1; off < 64; off <<= 1) {
            float yg = __shfl_up(xg, off, 64);
            if (lane >= off) xg += yg;
        }
        gc[lane] = xg;
    }

    floatx4 kkf[4], qkf[4];
#pragma unroll
    for (int nt = 0; nt < 4; nt++) { kkf[nt] = (floatx4){0,0,0,0}; qkf[nt] = (floatx4){0,0,0,0}; }
#pragma unroll
    for (int kk = 0; kk < 8; kk++) {
        short8 ak = *reinterpret_cast<const short8*>(Kb + (wave * 16 + l15) * 264 + kk * 32 + lh * 8);
        short8 aq = *reinterpret_cast<const short8*>(Qb + (wave * 16 + l15) * 264 + kk * 32 + lh * 8);
#pragma unroll
        for (int nt = 0; nt < 4; nt++) {
            short8 bk = *reinterpret_cast<const short8*>(Kb + (nt * 16 + l15) * 264 + kk * 32 + lh * 8);
            kkf[nt] = __builtin_amdgcn_mfma_f32_16x16x32_bf16(ak, bk, kkf[nt], 0, 0, 0);
            qkf[nt] = __builtin_amdgcn_mfma_f32_16x16x32_bf16(aq, bk, qkf[nt], 0, 0, 0);
        }
    }
    __syncthreads();

    {
        int r = tid >> 2, seg = (tid & 3) * 64;
        float gmm = __expf(gc[r]);
        float qs = SCALE_ * gmm, ksc = bb_s[r] * gmm;
#pragma unroll
        for (int jj = 0; jj < 8; jj++) {
            Pk8 qi, ki, qo, ko;
            qi.v = *reinterpret_cast<const uint4v*>(Qb + r * 264 + seg + jj * 8);
            ki.v = *reinterpret_cast<const uint4v*>(Kb + r * 264 + seg + jj * 8);
#pragma unroll
            for (int e = 0; e < 8; e++) {
                qo.us[e] = f32_to_bf16(bf16_to_f32(qi.us[e]) * qs);
                ko.us[e] = f32_to_bf16(bf16_to_f32(ki.us[e]) * ksc);
            }
            *reinterpret_cast<uint4v*>(Qg + idx * 16384 + r * 256 + seg + jj * 8) = qo.v;
            *reinterpret_cast<uint4v*>(KB + idx * 16384 + r * 256 + seg + jj * 8) = ko.v;
        }
    }
    if (tid < 64) es[tid] = __expf(gc[63] - gc[tid]);
    __syncthreads();

#pragma unroll
    for (int nt = 0; nt < 4; nt++)
#pragma unroll
        for (int j = 0; j < 4; j++) {
            int t2 = wave * 16 + lh * 4 + j;
            int s2 = nt * 16 + l15;
            float dec = (s2 <= t2) ? __expf(gc[t2] - gc[s2]) : 0.f;
            Msf[t2 * 65 + s2] = (s2 < t2) ? bb_s[t2] * dec * kkf[nt][j] : 0.f;
            float av = (s2 <= t2) ? SCALE_ * dec * qkf[nt][j] : 0.f;
            Am[idx * 4096 + t2 * 64 + s2] = f32_to_bf16(av);
        }
    __syncthreads();

    {
        int t = lane;
        float a[16];
#pragma unroll
        for (int j2 = 0; j2 < 16; j2++) a[j2] = 0.f;
        float mcur = Msf[t * 65 + 0];
        for (int s = 0; s < 63; s++) {
            float mnext = Msf[t * 65 + s + 1];
            float m = (t > s) ? mcur : 0.f;
#pragma unroll
            for (int j2 = 0; j2 < 16; j2++) {
                int jg = 4 * j2 + wave;
                if (jg < s) {
                    float ra = __int_as_float(
                        __builtin_amdgcn_readlane(__float_as_int(a[j2]), s));
                    a[j2] = fmaf(m, -ra, a[j2]);
                } else if (jg == s) {
                    a[j2] += m;
                }
            }
            mcur = mnext;
        }
#pragma unroll
        for (int j2 = 0; j2 < 16; j2++) {
            int jg = 4 * j2 + wave;
            float v = (t == jg) ? 1.f : ((jg < t) ? -a[j2] : 0.f);
            Ts_lds[t * 72 + jg] = f32_to_bf16(v);
        }
    }
    __syncthreads();

    {
        int rr = tid >> 2, sseg = (tid & 3) * 16;
        *reinterpret_cast<uint4v*>(Tm + idx * 4096 + rr * 64 + sseg) =
            *reinterpret_cast<const uint4v*>(Ts_lds + rr * 72 + sseg);
        *reinterpret_cast<uint4v*>(Tm + idx * 4096 + rr * 64 + sseg + 8) =
            *reinterpret_cast<const uint4v*>(Ts_lds + rr * 72 + sseg + 8);
    }
    {
        int dk = tid;
#pragma unroll
        for (int sb = 0; sb < 8; sb++) {
            Pk8 pk;
#pragma unroll
            for (int e = 0; e < 8; e++) {
                int s = sb * 8 + e;
                pk.us[e] = f32_to_bf16(bf16_to_f32(Kb[s * 264 + dk]) * es[s]);
            }
            *reinterpret_cast<uint4v*>(KlT + idx * 16384 + dk * 64 + sb * 8) = pk.v;
        }
    }
    for (int hv = 0; hv < 2; hv++) {
        __syncthreads();
        int r = tid >> 2, seg = (tid & 3) * 64;
        const float* vsrc = VC + (size_t)(bt0 + r) * VAL_DIM + h * DV + hv * 256 + seg;
#pragma unroll
        for (int jj = 0; jj < 16; jj++)
            *reinterpret_cast<float4*>(Vst + r * 264 + seg + jj * 4) =
                *reinterpret_cast<const float4*>(vsrc + jj * 4);
        __syncthreads();
#pragma unroll
        for (int sb = 0; sb < 8; sb++) {
            Pk8 pk;
#pragma unroll
            for (int e = 0; e < 8; e++) {
                int s = sb * 8 + e;
                pk.us[e] = f32_to_bf16(Vst[s * 264 + tid] * bb_s[s]);
            }
            *reinterpret_cast<uint4v*>(BVT + idx * 32768 + (size_t)(hv * 256 + tid) * 64 + sb * 8) = pk.v;
        }
    }
    if (tid == 0) gend[idx] = __expf(gc[63]);
}

// Pass 2: sequential over chunks; 512-thread blocks, 8 waves =
// (2 dv-strips of 16) x (4 t-quarters of 16). Each wave owns a persistent
// 16dv x 64dk state accumulator (dk range = t-quarter index * 64).
// Grid: 1-D 192 with XCD-grouping remap so the 16 dv-slices of one bh
// share an XCD's L2 (cuts shared-operand HBM re-fetch).
__global__ __launch_bounds__(512, 1) void chunk_scan_kernel(
    const unsigned short* __restrict__ Qg, const unsigned short* __restrict__ KBp,
    const unsigned short* __restrict__ KlTp, const unsigned short* __restrict__ Tmp_,
    const unsigned short* __restrict__ Amp_, const unsigned short* __restrict__ BVTp,
    const float* __restrict__ gendp, float* __restrict__ O) {
    int bid = blockIdx.x;                 // 0..191
    int xs = bid & 7, js = bid >> 3;      // XCD slot, slot-local index
    int L = xs * 24 + js;                 // group same-bh blocks per XCD
    int bh = L >> 4, slice = L & 15;
    int b = bh / NH, h = bh % NH;
    int dvbase = slice * 32;
    int tid = threadIdx.x, wave = tid >> 6, lane = tid & 63;
    int l15 = lane & 15, lh = lane >> 4;
    int ms = wave >> 2;                   // dv strip (0/1)
    int ns = wave & 3;                    // t quarter (also dk range for state)
    int tb = ns * 16;

    __shared__ __align__(16) unsigned short QgB[64 * 264];
    __shared__ __align__(16) unsigned short KBB[64 * 264];
    __shared__ __align__(16) unsigned short KlTB[256 * 72];
    __shared__ __align__(16) unsigned short SbT[32 * 264];
    __shared__ __align__(16) unsigned short Wb[32 * 72];
    __shared__ __align__(16) unsigned short Ub[32 * 72];
    __shared__ __align__(16) float Ost[64 * 36];

    floatx4 st[4];
#pragma unroll
    for (int i = 0; i < 4; i++) st[i] = (floatx4){0.f, 0.f, 0.f, 0.f};
    for (int i = tid; i < 32 * 264; i += 512) SbT[i] = 0;

    int sr = tid >> 3, sseg = (tid & 7) * 32;   // Qg/KB staging coords
    int kr = tid >> 1, kseg = (tid & 1) * 32;   // KlT staging coords (kr 0..255)
    size_t idx0 = (size_t)bh * NC;

    uint4v qv[4], kv[4], klv[4];
    {
        const unsigned short* qg0 = Qg + idx0 * 16384;
        const unsigned short* kb0 = KBp + idx0 * 16384;
        const unsigned short* kl0 = KlTp + idx0 * 16384;
#pragma unroll
        for (int j = 0; j < 4; j++) {
            qv[j] = *reinterpret_cast<const uint4v*>(qg0 + sr * 256 + sseg + j * 8);
            kv[j] = *reinterpret_cast<const uint4v*>(kb0 + sr * 256 + sseg + j * 8);
            klv[j] = *reinterpret_cast<const uint4v*>(kl0 + kr * 64 + kseg + j * 8);
        }
    }

    for (int c = 0; c < NC; c++) {
        size_t idx = idx0 + c;
        const unsigned short* tm = Tmp_ + idx * 4096;
        const unsigned short* am = Amp_ + idx * 4096;
        const unsigned short* bvt = BVTp + idx * 32768;
        float ge = gendp[idx];

        __syncthreads();   // (1) prior chunk's reads of staging/Ost done
#pragma unroll
        for (int j = 0; j < 4; j++) {
            *reinterpret_cast<uint4v*>(QgB + sr * 264 + sseg + j * 8) = qv[j];
            *reinterpret_cast<uint4v*>(KBB + sr * 264 + sseg + j * 8) = kv[j];
            *reinterpret_cast<uint4v*>(KlTB + kr * 72 + kseg + j * 8) = klv[j];
        }
        __syncthreads();   // (2) staging visible

        // prefetch next chunk's staging (overlaps with phase A+ compute)
        if (c + 1 < NC) {
            const unsigned short* qg2 = Qg + (idx + 1) * 16384;
            const unsigned short* kb2 = KBp + (idx + 1) * 16384;
            const unsigned short* kl2 = KlTp + (idx + 1) * 16384;
#pragma unroll
            for (int j = 0; j < 4; j++) {
                qv[j] = *reinterpret_cast<const uint4v*>(qg2 + sr * 256 + sseg + j * 8);
                kv[j] = *reinterpret_cast<const uint4v*>(kb2 + sr * 256 + sseg + j * 8);
                klv[j] = *reinterpret_cast<const uint4v*>(kl2 + kr * 64 + kseg + j * 8);
            }
        }

        // per-wave operands (current chunk; L2-warm, shared across slices)
        short8 tfr[2], afr[2];
#pragma unroll
        for (int kk = 0; kk < 2; kk++) {
            tfr[kk] = *reinterpret_cast<const short8*>(tm + (tb + l15) * 64 + kk * 32 + lh * 8);
            afr[kk] = *reinterpret_cast<const short8*>(am + (tb + l15) * 64 + kk * 32 + lh * 8);
        }
        float bvv[4];
#pragma unroll
        for (int j = 0; j < 4; j++)
            bvv[j] = bf16_to_f32(bvt[(size_t)(dvbase + ms * 16 + lh * 4 + j) * 64 + tb + l15]);

        // -------- phase A: X2 = S^T*Qg, X1 = S^T*KB ([16dv x 16t] per wave) --------
        floatx4 x2f = (floatx4){0,0,0,0}, x1f = (floatx4){0,0,0,0};
#pragma unroll
        for (int kk = 0; kk < 8; kk++) {
            short8 af = *reinterpret_cast<const short8*>(SbT + (ms * 16 + l15) * 264 + kk * 32 + lh * 8);
            short8 bq = *reinterpret_cast<const short8*>(QgB + (tb + l15) * 264 + kk * 32 + lh * 8);
            short8 bk = *reinterpret_cast<const short8*>(KBB + (tb + l15) * 264 + kk * 32 + lh * 8);
            x2f = __builtin_amdgcn_mfma_f32_16x16x32_bf16(af, bq, x2f, 0, 0, 0);
            x1f = __builtin_amdgcn_mfma_f32_16x16x32_bf16(af, bk, x1f, 0, 0, 0);
        }
        // W = BV - X1
#pragma unroll
        for (int j = 0; j < 4; j++)
            Wb[(ms * 16 + lh * 4 + j) * 72 + tb + l15] = f32_to_bf16(bvv[j] - x1f[j]);
        __syncthreads();   // (3) W full-t visible

        // -------- phase B: U = W * T ([16dv x 16t] per wave) --------
        floatx4 uf = (floatx4){0,0,0,0};
#pragma unroll
        for (int kk = 0; kk < 2; kk++) {
            short8 af = *reinterpret_cast<const short8*>(Wb + (ms * 16 + l15) * 72 + kk * 32 + lh * 8);
            uf = __builtin_amdgcn_mfma_f32_16x16x32_bf16(af, tfr[kk], uf, 0, 0, 0);
        }
#pragma unroll
        for (int j = 0; j < 4; j++)
            Ub[(ms * 16 + lh * 4 + j) * 72 + tb + l15] = f32_to_bf16(uf[j]);
        __syncthreads();   // (4) U full-t visible

        // -------- phase C: S = gend*S + U*KlT ([16dv x 64dk] per wave) --------
#pragma unroll
        for (int i = 0; i < 4; i++) st[i] = st[i] * ge;
#pragma unroll
        for (int kk = 0; kk < 2; kk++) {
            short8 af = *reinterpret_cast<const short8*>(Ub + (ms * 16 + l15) * 72 + kk * 32 + lh * 8);
#pragma unroll
            for (int dkt = 0; dkt < 4; dkt++) {
                short8 bf = *reinterpret_cast<const short8*>(KlTB + (ns * 64 + dkt * 16 + l15) * 72 + kk * 32 + lh * 8);
                st[dkt] = __builtin_amdgcn_mfma_f32_16x16x32_bf16(af, bf, st[dkt], 0, 0, 0);
            }
        }
        // bf16 shadow for next chunk
#pragma unroll
        for (int dkt = 0; dkt < 4; dkt++)
#pragma unroll
            for (int j = 0; j < 4; j++)
                SbT[(ms * 16 + lh * 4 + j) * 264 + ns * 64 + dkt * 16 + l15] = f32_to_bf16(st[dkt][j]);

        // -------- phase D: O = X2 + U*A --------
#pragma unroll
        for (int kk = 0; kk < 2; kk++) {
            short8 af = *reinterpret_cast<const short8*>(Ub + (ms * 16 + l15) * 72 + kk * 32 + lh * 8);
            x2f = __builtin_amdgcn_mfma_f32_16x16x32_bf16(af, afr[kk], x2f, 0, 0, 0);
        }
#pragma unroll
        for (int j = 0; j < 4; j++)
            Ost[(tb + l15) * 36 + ms * 16 + lh * 4 + j] = x2f[j];
        __syncthreads();   // (5) Ost visible

        // coalesced store: 512 threads x 16B
        {
            int tr = tid >> 3, dvs = (tid & 7) * 4;
            float4 ov = *reinterpret_cast<const float4*>(Ost + tr * 36 + dvs);
            size_t ga = ((size_t)(b * T_ + c * CC + tr)) * VAL_DIM + h * DV + dvbase + dvs;
            *reinterpret_cast<float4*>(O + ga) = ov;
        }
    }
}

// ---------------- gated RMSNorm * w * silu(g) -> bf16 ----------------
__global__ __launch_bounds__(256) void gated_norm_kernel(const float* __restrict__ o,
                                                         const float* __restrict__ g,
                                                         const float* __restrict__ nw,
                                                         unsigned short* __restrict__ out) {
    int bt = blockIdx.x, h = blockIdx.y, tid = threadIdx.x;
    const float* orow = o + (size_t)bt * VAL_DIM + h * DV;
    const float* grow = g + (size_t)bt * VAL_DIM + h * DV;
    float x0 = orow[tid], x1 = orow[tid + 256];
    float ss = x0 * x0 + x1 * x1;
#pragma unroll
    for (int m = 1; m < 64; m <<= 1) ss += __shfl_xor(ss, m);
    __shared__ float wsum[4];
    if ((tid & 63) == 0) wsum[tid >> 6] = ss;
    __syncthreads();
    float tot = wsum[0] + wsum[1] + wsum[2] + wsum[3];
    float r = rsqrtf(tot / (float)DV + EPS_);
    float o0 = x0 * r * nw[tid] * silu_f(grow[tid]);
    float o1 = x1 * r * nw[tid + 256] * silu_f(grow[tid + 256]);
    unsigned short* orow_o = out + (size_t)bt * VAL_DIM + h * DV;
    orow_o[tid] = f32_to_bf16(o0);
    orow_o[tid + 256] = f32_to_bf16(o1);
}

extern "C" void kernel_launch(void* const* d_in, const int* in_sizes, int n_in,
                              void* d_out, int out_size, void* d_ws, size_t ws_size,
                              hipStream_t stream) {
    const float* x     = (const float*)d_in[0];
    const float* w_q   = (const float*)d_in[1];
    const float* w_k   = (const float*)d_in[2];
    const float* w_v   = (const float*)d_in[3];
    const float* w_a   = (const float*)d_in[4];
    const float* w_b   = (const float*)d_in[5];
    const float* w_g   = (const float*)d_in[6];
    const float* w_o   = (const float*)d_in[7];
    const float* cq    = (const float*)d_in[8];
    const float* ck    = (const float*)d_in[9];
    const float* cv    = (const float*)d_in[10];
    const float* A_log = (const float*)d_in[11];
    const float* dtb   = (const float*)d_in[12];
    const float* nw    = (const float*)d_in[13];
    float* out = (float*)d_out;

    char* ws = (char*)d_ws;
    size_t off = 0;
    auto alloc = [&](size_t bytes) {
        char* p = ws + off;
        off += (bytes + 255) & ~(size_t)255;
        return p;
    };
    unsigned short* xb = (unsigned short*)alloc((size_t)MT * HID * 2);
    unsigned short* wT = (unsigned short*)alloc((size_t)VAL_DIM * HID * 2);
    float* P1 = (float*)alloc((size_t)MT * KEY_DIM * 4);
    float* QC = (float*)alloc((size_t)MT * KEY_DIM * 4);
    float* KC = (float*)alloc((size_t)MT * KEY_DIM * 4);
    float* P2 = (float*)alloc((size_t)MT * VAL_DIM * 4);
    float* VC = (float*)alloc((size_t)MT * VAL_DIM * 4);
    float* GL = (float*)alloc((size_t)MT * NH * 4);
    float* BE = (float*)alloc((size_t)MT * NH * 4);
    const int NCH = 12 * NC;
    unsigned short* KlT = (unsigned short*)alloc((size_t)NCH * 256 * 64 * 2);
    unsigned short* Tm  = (unsigned short*)alloc((size_t)NCH * 4096 * 2);
    unsigned short* Am  = (unsigned short*)alloc((size_t)NCH * 4096 * 2);
    unsigned short* BVT = (unsigned short*)alloc((size_t)NCH * 512 * 64 * 2);
    float* gend = (float*)alloc((size_t)NCH * 4);

    unsigned short* Qg = (unsigned short*)P1;
    unsigned short* KB = (unsigned short*)P1 + (size_t)NCH * 16384;
    float* OB = VC;
    unsigned short* ONB = (unsigned short*)P1;

    // x -> bf16
    cvt_bf16_kernel<<<(MT * HID) / 1024, 256, 0, stream>>>(x, xb, MT * HID);

    // q path
    transpose_cvt_kernel<<<dim3(HID / 64, KEY_DIM / 64), 256, 0, stream>>>(w_q, wT, HID, KEY_DIM);
    gemm_bf16_kernel<<<dim3(KEY_DIM / BN, MT / BM), 256, 0, stream>>>(xb, wT, P1, MT, KEY_DIM, HID);
    conv_silu_l2norm_kernel<<<dim3(MT, NH), 256, 0, stream>>>(P1, cq, QC);

    // k path
    transpose_cvt_kernel<<<dim3(HID / 64, KEY_DIM / 64), 256, 0, stream>>>(w_k, wT, HID, KEY_DIM);
    gemm_bf16_kernel<<<dim3(KEY_DIM / BN, MT / BM), 256, 0, stream>>>(xb, wT, P1, MT, KEY_DIM, HID);
    conv_silu_l2norm_kernel<<<dim3(MT, NH), 256, 0, stream>>>(P1, ck, KC);

    // v path
    transpose_cvt_kernel<<<dim3(HID / 64, VAL_DIM / 64), 256, 0, stream>>>(w_v, wT, HID, VAL_DIM);
    gemm_bf16_kernel<<<dim3(VAL_DIM / BN, MT / BM), 256, 0, stream>>>(xb, wT, P2, MT, VAL_DIM, HID);
    conv_silu_kernel<<<dim3(MT, VAL_DIM / 256), 256, 0, stream>>>(P2, cv, VC);

    // g path
    transpose_cvt_kernel<<<dim3(HID / 64, VAL_DIM / 64), 256, 0, stream>>>(w_g, wT, HID, VAL_DIM);
    gemm_bf16_kernel<<<dim3(VAL_DIM / BN, MT / BM), 256, 0, stream>>>(xb, wT, P2, MT, VAL_DIM, HID);

    // a/b projections (f32, exact)
    ab_kernel<<<MT, 256, 0, stream>>>(x, w_a, w_b, A_log, dtb, GL, BE);

    // chunked scan
    chunk_prep_kernel<<<dim3(NC, 12), 256, 0, stream>>>(QC, KC, VC, GL, BE,
                                                        Qg, KB, KlT, Tm, Am, BVT, gend);
    chunk_scan_kernel<<<192, 512, 0, stream>>>(Qg, KB, KlT, Tm, Am, BVT, gend, OB);

    // gated RMSNorm -> bf16
    gated_norm_kernel<<<dim3(MT, NH), 256, 0, stream>>>(OB, P2, nw, ONB);

    // output projection
    transpose_cvt_kernel<<<dim3(VAL_DIM / 64, HID / 64), 256, 0, stream>>>(w_o, wT, VAL_DIM, HID);
    gemm_bf16_kernel<<<dim3(HID / BN, MT / BM), 256, 0, stream>>>(ONB, wT, out, MT, HID, VAL_DIM);
}